// Round 16
// baseline (205.738 us; speedup 1.0000x reference)
//
#include <hip/hip_runtime.h>

typedef unsigned short u16;
typedef unsigned long long u64;
typedef __attribute__((ext_vector_type(4))) unsigned u32x4;
typedef __attribute__((ext_vector_type(4))) float f32x4;
typedef __attribute__((ext_vector_type(16))) float f32x16;
typedef __attribute__((ext_vector_type(8))) short s16x8;

#define DEV __device__ __forceinline__

DEV u16 bf16_rne(float f) {
    unsigned u = __builtin_bit_cast(unsigned, f);
    u += 0x7fffu + ((u >> 16) & 1u);
    return (u16)(u >> 16);
}
DEV unsigned cvt_pk_bf16(float lo, float hi) {   // packed f32x2 -> bf16x2 (1 instr)
    unsigned r;
    asm("v_cvt_pk_bf16_f32 %0, %1, %2" : "=v"(r) : "v"(lo), "v"(hi));
    return r;
}
DEV void gload_lds16(const void* g, void* l) {
    __builtin_amdgcn_global_load_lds((const __attribute__((address_space(1))) void*)g,
                                     (__attribute__((address_space(3))) void*)l, 16, 0, 0);
}

// ---------------- fused f32 -> bf16 convert for all 4 tensors (1 launch) ----------------
__global__ __launch_bounds__(256)
void cvt_all(const float* __restrict__ x, const float* __restrict__ qw,
             const float* __restrict__ kvw, const float* __restrict__ ow,
             u16* __restrict__ xo, u16* __restrict__ qo,
             u16* __restrict__ kvo, u16* __restrict__ oo) {
    const int i = blockIdx.x * 256 + threadIdx.x;   // 4,456,448 chunks exactly
    const float* src; u16* dst; int off;
    if (i < 2097152)      { src = x;   dst = xo;  off = i; }
    else if (i < 3145728) { src = qw;  dst = qo;  off = i - 2097152; }
    else if (i < 3407872) { src = kvw; dst = kvo; off = i - 3145728; }
    else                  { src = ow;  dst = oo;  off = i - 3407872; }
    f32x4 v = ((const f32x4*)src)[off];
    unsigned d0 = cvt_pk_bf16(v[0], v[1]);
    unsigned d1 = cvt_pk_bf16(v[2], v[3]);
    ((u64*)dst)[off] = (u64)d0 | ((u64)d1 << 32);
}

// ====== 256x128-tile 8-wave GEMM, phase-split K-step (R16) ======
// Per K-step: {ks0 frag reads -> stage(t+1) into other buffer -> 16 MFMA (compiler-
// paced lgkmcnt) -> ks1 frag reads -> 16 MFMA -> vmcnt(0)+lgkmcnt(0) -> s_barrier}.
// One barrier per K-step. Stage never targets the buffer being read (prefetch dist 1);
// the tail drain+barrier seals reads before the buffer is restaged next iter, and
// certifies all waves' stage loads landed before they are read.
template<int MODE>
__global__ __launch_bounds__(512, 1)
void gemm_bt2(const u16* __restrict__ A, const u16* __restrict__ B,
              const float* __restrict__ bias, void* __restrict__ Cout,
              const float* __restrict__ cosb, const float* __restrict__ sinb,
              float scale, int M, int N, int K) {
    __shared__ u16 Abuf[2][256 * 64];
    __shared__ u16 Bbuf[2][128 * 64];
    const int tid = threadIdx.x;
    const int w = tid >> 6, l = tid & 63;
    const int lr = l & 15, lg = l >> 4;
    const int wm = w >> 1, wn = w & 1;
    const int nbn = N >> 7;
    const int bm = blockIdx.x / nbn, bn = blockIdx.x % nbn;
    const int NT = K >> 6;
    const int rsel = l >> 3;
    const int csw = (l & 7) ^ rsel;   // inverse-swizzled source chunk (rule 21)
    const u16* Ag = A + ((size_t)(bm * 256) + rsel) * K + csw * 8;
    const u16* Bg = B + ((size_t)(bn * 128) + rsel) * K + csw * 8;

    f32x4 acc[4][4] = {};

#define STAGE(t, bufi) {                                                              \
        const int k0_ = (t) * 64;                                                     \
        _Pragma("unroll")                                                             \
        for (int j = 0; j < 4; ++j)                                                   \
            gload_lds16(Ag + (size_t)(w * 32 + j * 8) * K + k0_,                      \
                        &Abuf[bufi][(w * 32 + j * 8) * 64]);                          \
        _Pragma("unroll")                                                             \
        for (int j = 0; j < 2; ++j)                                                   \
            gload_lds16(Bg + (size_t)(w * 16 + j * 8) * K + k0_,                      \
                        &Bbuf[bufi][(w * 16 + j * 8) * 64]);                          \
    }

    STAGE(0, 0);
    asm volatile("s_waitcnt vmcnt(0)" ::: "memory");
    __builtin_amdgcn_s_barrier();

    #pragma unroll 2
    for (int t = 0; t < NT; ++t) {
        const int bufi = t & 1;
        s16x8 af[2][4], bf[2][4];

        // ---- phase 1: ks0 fragment reads, then stage(t+1) into the other buffer
        #pragma unroll
        for (int mi = 0; mi < 4; ++mi) {
            const int row = wm * 64 + mi * 16 + lr;
            const int off = (row * 64 + lg * 8) ^ ((row & 7) << 3);
            af[0][mi] = *(const s16x8*)&Abuf[bufi][off];
        }
        #pragma unroll
        for (int ni = 0; ni < 4; ++ni) {
            const int row = wn * 32 + (ni & 1) * 16 + (ni >> 1) * 64 + lr;
            const int off = (row * 64 + lg * 8) ^ ((row & 7) << 3);
            bf[0][ni] = *(const s16x8*)&Bbuf[bufi][off];
        }
        if (t + 1 < NT) STAGE(t + 1, bufi ^ 1);

        __builtin_amdgcn_s_setprio(1);
        #pragma unroll
        for (int mi = 0; mi < 4; ++mi)
            #pragma unroll
            for (int ni = 0; ni < 4; ++ni)
                acc[mi][ni] = __builtin_amdgcn_mfma_f32_16x16x32_bf16(af[0][mi], bf[0][ni], acc[mi][ni], 0, 0, 0);
        __builtin_amdgcn_s_setprio(0);

        // ---- phase 2: ks1 fragment reads + MFMA
        #pragma unroll
        for (int mi = 0; mi < 4; ++mi) {
            const int row = wm * 64 + mi * 16 + lr;
            const int off = (row * 64 + 32 + lg * 8) ^ ((row & 7) << 3);
            af[1][mi] = *(const s16x8*)&Abuf[bufi][off];
        }
        #pragma unroll
        for (int ni = 0; ni < 4; ++ni) {
            const int row = wn * 32 + (ni & 1) * 16 + (ni >> 1) * 64 + lr;
            const int off = (row * 64 + 32 + lg * 8) ^ ((row & 7) << 3);
            bf[1][ni] = *(const s16x8*)&Bbuf[bufi][off];
        }
        __builtin_amdgcn_s_setprio(1);
        #pragma unroll
        for (int mi = 0; mi < 4; ++mi)
            #pragma unroll
            for (int ni = 0; ni < 4; ++ni)
                acc[mi][ni] = __builtin_amdgcn_mfma_f32_16x16x32_bf16(af[1][mi], bf[1][ni], acc[mi][ni], 0, 0, 0);
        __builtin_amdgcn_s_setprio(0);

        // ---- tail: own stage loads landed + own reads drained; barrier makes global
        asm volatile("s_waitcnt vmcnt(0) lgkmcnt(0)" ::: "memory");
        __builtin_amdgcn_s_barrier();
    }
#undef STAGE

    if (MODE == 0) {
        // fused bias + RoPE + scale, bf16 out
        #pragma unroll
        for (int ni = 0; ni < 2; ++ni) {
            const int d = wn * 32 + ni * 16 + lr;            // [0,64)
            const int col = bn * 128 + d;
            const float bv0 = bias[col];
            const float bv1 = bias[col + 64];
            #pragma unroll
            for (int mi = 0; mi < 4; ++mi) {
                #pragma unroll
                for (int r = 0; r < 4; ++r) {
                    const int row = bm * 256 + wm * 64 + mi * 16 + lg * 4 + r;
                    const int s = row & 2047;
                    const float c0 = cosb[s * 128 + d],      s0 = sinb[s * 128 + d];
                    const float c1 = cosb[s * 128 + d + 64], s1 = sinb[s * 128 + d + 64];
                    const float t0 = acc[mi][ni][r] + bv0;
                    const float t1 = acc[mi][ni + 2][r] + bv1;
                    ((u16*)Cout)[(size_t)row * N + col]      = bf16_rne((t0 * c0 - t1 * s0) * scale);
                    ((u16*)Cout)[(size_t)row * N + col + 64] = bf16_rne((t1 * c1 + t0 * s1) * scale);
                }
            }
        }
    } else {
        #pragma unroll
        for (int ni = 0; ni < 4; ++ni) {
            const int col = bn * 128 + wn * 32 + (ni & 1) * 16 + (ni >> 1) * 64 + lr;
            #pragma unroll
            for (int mi = 0; mi < 4; ++mi) {
                #pragma unroll
                for (int r = 0; r < 4; ++r) {
                    const int row = bm * 256 + wm * 64 + mi * 16 + lg * 4 + r;
                    ((float*)Cout)[(size_t)row * N + col] = acc[mi][ni][r];
                }
            }
        }
    }
}

// ---------------- KV-proj GEMM: 64x128 tile, 4-wave, grid 256 (R15) ----------------
__global__ __launch_bounds__(256)
void gemm_kv(const u16* __restrict__ A, const u16* __restrict__ B,
             const float* __restrict__ bias, void* __restrict__ Cout,
             void* __restrict__ Cout2, const float* __restrict__ cosb,
             const float* __restrict__ sinb, int M, int N, int K) {
    __shared__ u16 As[64 * 64];
    __shared__ u16 Bs[128 * 64];
    const int tid = threadIdx.x;
    const int w = tid >> 6, l = tid & 63;
    const int nbn = N >> 7;                // 4
    const int bm = blockIdx.x / nbn;       // [0,64)
    const int bn = blockIdx.x % nbn;
    const int wr = w >> 1, wc = w & 1;
    const int lr = l & 15, lg = l >> 4;
    const int rowsel = l >> 3;
    const int csw = (l & 7) ^ rowsel;   // inverse-swizzled source chunk (rule 21)
    const int rxor = (lr & 7) << 3;     // read-side XOR

    f32x4 acc[2][4] = {};

    const u16* Abase = A + (size_t)(bm * 64 + w * 16) * K;
    const u16* Bbase = B + (size_t)(bn * 128 + w * 32) * K;
    u16* AsW = As + (w * 16) * 64;
    u16* BsW = Bs + (w * 32) * 64;

    for (int k0 = 0; k0 < K; k0 += 64) {
        __syncthreads();
        #pragma unroll
        for (int i = 0; i < 2; ++i)
            gload_lds16(Abase + (size_t)(i * 8 + rowsel) * K + k0 + csw * 8, AsW + i * 8 * 64);
        #pragma unroll
        for (int i = 0; i < 4; ++i)
            gload_lds16(Bbase + (size_t)(i * 8 + rowsel) * K + k0 + csw * 8, BsW + i * 8 * 64);
        __syncthreads();
        #pragma unroll
        for (int ks = 0; ks < 2; ++ks) {
            s16x8 af[2], bfr[4];
            #pragma unroll
            for (int mi = 0; mi < 2; ++mi)
                af[mi] = *(const s16x8*)(As + (((wr * 32 + mi * 16 + lr) * 64 + ks * 32 + lg * 8) ^ rxor));
            #pragma unroll
            for (int ni = 0; ni < 4; ++ni)
                bfr[ni] = *(const s16x8*)(Bs + (((wc * 32 + (ni & 1) * 16 + (ni >> 1) * 64 + lr) * 64 + ks * 32 + lg * 8) ^ rxor));
            #pragma unroll
            for (int mi = 0; mi < 2; ++mi)
                #pragma unroll
                for (int ni = 0; ni < 4; ++ni)
                    acc[mi][ni] = __builtin_amdgcn_mfma_f32_16x16x32_bf16(af[mi], bfr[ni], acc[mi][ni], 0, 0, 0);
        }
    }

    const int row0 = bm * 64 + wr * 32;
    const int bb = row0 >> 11;
    if (bn < 2) {
        // K head kvh = bn, with fused RoPE (scale 1): pairs (ni, ni+2)
        #pragma unroll
        for (int ni = 0; ni < 2; ++ni) {
            const int d = wc * 32 + ni * 16 + lr;            // [0,64)
            const float bv0 = bias[bn * 128 + d];
            const float bv1 = bias[bn * 128 + d + 64];
            u16* kbase = (u16*)Cout + (size_t)(bb * 2 + bn) * 2048 * 128;
            #pragma unroll
            for (int mi = 0; mi < 2; ++mi) {
                #pragma unroll
                for (int r = 0; r < 4; ++r) {
                    const int s = (row0 & 2047) + mi * 16 + lg * 4 + r;
                    const float c0 = cosb[s * 128 + d],      s0 = sinb[s * 128 + d];
                    const float c1 = cosb[s * 128 + d + 64], s1 = sinb[s * 128 + d + 64];
                    const float t0 = acc[mi][ni][r] + bv0;
                    const float t1 = acc[mi][ni + 2][r] + bv1;
                    kbase[(size_t)s * 128 + d]      = bf16_rne(t0 * c0 - t1 * s0);
                    kbase[(size_t)s * 128 + d + 64] = bf16_rne(t1 * c1 + t0 * s1);
                }
            }
        }
    } else {
        // V^T [b][kvh][d][s], packed 4-row bf16 writes
        #pragma unroll
        for (int ni = 0; ni < 4; ++ni) {
            const int d = wc * 32 + (ni & 1) * 16 + (ni >> 1) * 64 + lr;
            const int kvh = bn - 2;
            const float bv = bias[256 + kvh * 128 + d];
            #pragma unroll
            for (int mi = 0; mi < 2; ++mi) {
                const int s = (row0 & 2047) + mi * 16 + lg * 4;
                unsigned d0 = cvt_pk_bf16(acc[mi][ni][0] + bv, acc[mi][ni][1] + bv);
                unsigned d1 = cvt_pk_bf16(acc[mi][ni][2] + bv, acc[mi][ni][3] + bv);
                *(u64*)((u16*)Cout2 + ((size_t)(bb * 2 + kvh) * 128 + d) * 2048 + s)
                    = (u64)d0 | ((u64)d1 << 32);
            }
        }
    }
}

// ---------------- causal GQA flash attention: 32x32 swapped-QK, in-register P (R15) ----
__global__ __launch_bounds__(256, 2)
void attn_fwd(const u16* __restrict__ Q, const u16* __restrict__ Kb,
              const u16* __restrict__ VTb, u16* __restrict__ O) {
    __shared__ u16 lds[2 * 64 * 128 + 2 * 128 * 64];   // K dbuf 32KB + V^T dbuf 32KB

    const int tid = threadIdx.x, w = tid >> 6, l = tid & 63;
    const int l31 = l & 31, hi = l >> 5;
    const int bi = blockIdx.x;
    const int half = bi >> 8, idx = bi & 255;
    const int bh = half * 16 + (idx >> 4);
    const int tq = idx & 15;
    const int tile = half ? (15 - tq) : tq;
    const int b = bh >> 4, h = bh & 15;
    const int kvh = h >> 3;
    const u16* Kg = Kb + (size_t)(b * 2 + kvh) * 2048 * 128;
    const u16* Vg = VTb + (size_t)(b * 2 + kvh) * 128 * 2048;

    // ---- Q fragments from global (L2-hot): lane q = l31, d = st*16 + hi*8 + j
    const int qrow = tile * 128 + w * 32 + l31;
    s16x8 qf[8];
    {
        const u16* Qrow = Q + ((size_t)(b * 2048 + qrow) * 2048 + h * 128);
        #pragma unroll
        for (int st = 0; st < 8; ++st)
            qf[st] = *(const s16x8*)(Qrow + st * 16 + hi * 8);
    }

    // stage K[64][128] + V^T[128][64] for k-tile kt into buffer (kt&1).
    auto stage = [&](int kt) {
        u16* Kd = lds + (kt & 1) * 8192;
        u16* Vd = lds + 16384 + (kt & 1) * 8192;
        #pragma unroll
        for (int j = 0; j < 4; ++j) {
            const int c = tid + j * 256;            // 1024 chunks: row = c>>4, col16 = c&15
            const int row = c >> 4;
            const int srcoff = ((c & 15) * 16) ^ ((row & 7) << 4);
            gload_lds16((const char*)Kg + (size_t)(kt * 64 + row) * 256 + srcoff,
                        (char*)Kd + c * 16);
        }
        #pragma unroll
        for (int j = 0; j < 4; ++j) {
            const int c = tid + j * 256;            // 1024 chunks: d = c>>3, k16 = c&7
            const int d = c >> 3;
            const int srcoff = ((c & 7) * 16) ^ ((d & 7) << 4);
            gload_lds16((const char*)Vg + (size_t)d * 4096 + (size_t)kt * 128 + srcoff,
                        (char*)Vd + c * 16);
        }
    };

    float m = -1e30f, lsum = 0.0f;
    f32x16 oacc[4] = {};

    const int ktend = 2 * tile + 2;
    stage(0);

    #pragma unroll 1
    for (int kt = 0; kt < ktend; ++kt) {
        const u16* Ks = lds + (kt & 1) * 8192;
        const u16* Vs = lds + 16384 + (kt & 1) * 8192;
        if (kt + 1 < ktend) {
            stage(kt + 1);                          // prefetch into other buffer
            asm volatile("s_waitcnt vmcnt(8)" ::: "memory");   // tile-kt landed
        } else {
            asm volatile("s_waitcnt vmcnt(0)" ::: "memory");
        }
        __builtin_amdgcn_s_barrier();               // raw: prefetch stays in flight

        // ---- swapped QK^T (32x32x16): S^T[k][q], A = K rows, B = Q cols
        f32x16 s0 = {}, s1 = {};
        #pragma unroll
        for (int st = 0; st < 8; ++st) {
            const int off0 = ((l31)*256 + st * 32 + hi * 16) ^ ((l31 & 7) << 4);
            const int off1 = ((l31 + 32) * 256 + st * 32 + hi * 16) ^ ((l31 & 7) << 4);
            s16x8 k0 = *(const s16x8*)((const char*)Ks + off0);
            s16x8 k1 = *(const s16x8*)((const char*)Ks + off1);
            s0 = __builtin_amdgcn_mfma_f32_32x32x16_bf16(k0, qf[st], s0, 0, 0, 0);
            s1 = __builtin_amdgcn_mfma_f32_32x32x16_bf16(k1, qf[st], s1, 0, 0, 0);
        }

        // ---- causal mask (only near diagonal) + online softmax, exp2 domain.
        if (kt >= 2 * tile) {
            #pragma unroll
            for (int r = 0; r < 16; ++r) {
                const int k0 = kt * 64 + (r & 3) + 8 * (r >> 2) + 4 * hi;
                if (k0 > qrow)      s0[r] = -1e30f;
                if (k0 + 32 > qrow) s1[r] = -1e30f;
            }
        }
        float mx = m;
        #pragma unroll
        for (int r = 0; r < 16; ++r) {
            mx = fmaxf(mx, s0[r]);
            mx = fmaxf(mx, s1[r]);
        }
        mx = fmaxf(mx, __shfl_xor(mx, 32, 64));     // combine lane halves (same q)
        const bool need = __any(mx > m + 11.5f);    // T13 defer-max (~8 nats)
        float corr = 1.0f;
        if (need) { corr = exp2f(m - mx); m = mx; }
        float rs = 0.0f;
        #pragma unroll
        for (int r = 0; r < 16; ++r) {
            const float p0 = exp2f(s0[r] - m);
            const float p1 = exp2f(s1[r] - m);
            s0[r] = p0; s1[r] = p1;
            rs += p0 + p1;
        }
        rs += __shfl_xor(rs, 32, 64);
        lsum = lsum * corr + rs;
        if (need) {                                 // rare: gather per-row corr
            #pragma unroll
            for (int r = 0; r < 16; ++r) {
                const int qr = (r & 3) + 8 * (r >> 2) + 4 * hi;
                const float cq = __shfl(corr, qr, 64);
                oacc[0][r] *= cq; oacc[1][r] *= cq;
                oacc[2][r] *= cq; oacc[3][r] *= cq;
            }
        }

        // ---- P -> PV A-frags in-register: 4 cvt_pk + 2 permlane32_swap per 16-k chunk
        s16x8 pa[4];
        #pragma unroll
        for (int c = 0; c < 4; ++c) {
            const int rb = (c & 1) * 8;
            float p0, p1, p2, p3, p4, p5, p6, p7;
            if (c < 2) {
                p0 = s0[rb+0]; p1 = s0[rb+1]; p2 = s0[rb+2]; p3 = s0[rb+3];
                p4 = s0[rb+4]; p5 = s0[rb+5]; p6 = s0[rb+6]; p7 = s0[rb+7];
            } else {
                p0 = s1[rb+0]; p1 = s1[rb+1]; p2 = s1[rb+2]; p3 = s1[rb+3];
                p4 = s1[rb+4]; p5 = s1[rb+5]; p6 = s1[rb+6]; p7 = s1[rb+7];
            }
            unsigned w01 = cvt_pk_bf16(p0, p1);     // lo: k(+0,+1) | hi: k(+4,+5)
            unsigned w23 = cvt_pk_bf16(p2, p3);
            unsigned w45 = cvt_pk_bf16(p4, p5);
            unsigned w67 = cvt_pk_bf16(p6, p7);
            asm volatile("v_permlane32_swap_b32 %0, %1" : "+v"(w01), "+v"(w45));
            asm volatile("v_permlane32_swap_b32 %0, %1" : "+v"(w23), "+v"(w67));
            u32x4 words = {w01, w23, w45, w67};     // k ascending: frag words 0..3
            pa[c] = __builtin_bit_cast(s16x8, words);
        }

        // ---- PV (32x32x16): O[q][d] += P[q][k] V[k][d]; B from swizzled V^T
        #pragma unroll
        for (int c = 0; c < 4; ++c) {
            #pragma unroll
            for (int nd = 0; nd < 4; ++nd) {
                const int row = nd * 32 + l31;
                const int boff = (row * 128 + c * 32 + hi * 16) ^ ((row & 7) << 4);
                s16x8 vf = *(const s16x8*)((const char*)Vs + boff);
                oacc[nd] = __builtin_amdgcn_mfma_f32_32x32x16_bf16(pa[c], vf, oacc[nd], 0, 0, 0);
            }
        }

        // reads of buf(kt&1) complete before next iter's stage lands there
        asm volatile("s_waitcnt lgkmcnt(0)" ::: "memory");
        __builtin_amdgcn_s_barrier();
    }

    // ---- epilogue: normalize (inv for row qr gathered from lane qr), write bf16
    const float inv = 1.0f / lsum;
    #pragma unroll
    for (int r = 0; r < 16; ++r) {
        const int qr = (r & 3) + 8 * (r >> 2) + 4 * hi;
        const float iq = __shfl(inv, qr, 64);
        const int q = tile * 128 + w * 32 + qr;
        u16* orow = O + ((size_t)(b * 2048 + q) * 2048 + h * 128 + l31);
        orow[0]  = bf16_rne(oacc[0][r] * iq);
        orow[32] = bf16_rne(oacc[1][r] * iq);
        orow[64] = bf16_rne(oacc[2][r] * iq);
        orow[96] = bf16_rne(oacc[3][r] * iq);
    }
}

// ---------------- launch ----------------
extern "C" void kernel_launch(void* const* d_in, const int* in_sizes, int n_in,
                              void* d_out, int out_size, void* d_ws, size_t ws_size,
                              hipStream_t stream) {
    const float* x    = (const float*)d_in[0];
    const float* cosb = (const float*)d_in[1];
    const float* sinb = (const float*)d_in[2];
    const float* q_w  = (const float*)d_in[3];
    const float* q_b  = (const float*)d_in[4];
    const float* kv_w = (const float*)d_in[5];
    const float* kv_b = (const float*)d_in[6];
    const float* o_w  = (const float*)d_in[7];
    float* out = (float*)d_out;

    char* p = (char*)d_ws;
    u16* x_bf   = (u16*)p; p += (size_t)4096 * 2048 * 2;
    u16* qw_bf  = (u16*)p; p += (size_t)2048 * 2048 * 2;
    u16* kvw_bf = (u16*)p; p += (size_t)512 * 2048 * 2;
    u16* ow_bf  = (u16*)p; p += (size_t)2048 * 2048 * 2;
    u16* q_bf   = (u16*)p; p += (size_t)4096 * 2048 * 2;
    u16* k_bf   = (u16*)p; p += (size_t)4 * 2048 * 128 * 2;   // [b][kvh][s][d]
    u16* vt_bf  = (u16*)p; p += (size_t)4 * 128 * 2048 * 2;   // [b][kvh][d][s]
    u16* at_bf  = (u16*)p; p += (size_t)4096 * 2048 * 2;

    cvt_all<<<17408, 256, 0, stream>>>(x, q_w, kv_w, o_w, x_bf, qw_bf, kvw_bf, ow_bf);

    // Q-proj with fused RoPE + score scaling (1/sqrt(128) * log2(e): exp2 domain)
    const float qk_scale2 = 0.12751744517764862f;
    gemm_bt2<0><<<dim3(16 * 16), 512, 0, stream>>>(x_bf, qw_bf, q_b, q_bf,
                                                   cosb, sinb, qk_scale2, 4096, 2048, 2048);
    gemm_kv<<<dim3(64 * 4), 256, 0, stream>>>(x_bf, kvw_bf, kv_b, k_bf, vt_bf,
                                              cosb, sinb, 4096, 512, 2048);

    attn_fwd<<<dim3(512), 256, 0, stream>>>(q_bf, k_bf, vt_bf, at_bf);

    gemm_bt2<1><<<dim3(16 * 16), 512, 0, stream>>>(at_bf, ow_bf, nullptr, out,
                                                   nullptr, nullptr, 0.0f, 4096, 2048, 2048);
}

// Round 17
// 195.124 us; speedup vs baseline: 1.0544x; 1.0544x over previous
//
#include <hip/hip_runtime.h>

typedef unsigned short u16;
typedef unsigned long long u64;
typedef __attribute__((ext_vector_type(4))) unsigned u32x4;
typedef __attribute__((ext_vector_type(4))) float f32x4;
typedef __attribute__((ext_vector_type(16))) float f32x16;
typedef __attribute__((ext_vector_type(8))) short s16x8;

#define DEV __device__ __forceinline__

DEV u16 bf16_rne(float f) {
    unsigned u = __builtin_bit_cast(unsigned, f);
    u += 0x7fffu + ((u >> 16) & 1u);
    return (u16)(u >> 16);
}
DEV unsigned cvt_pk_bf16(float lo, float hi) {   // packed f32x2 -> bf16x2 (1 instr)
    unsigned r;
    asm("v_cvt_pk_bf16_f32 %0, %1, %2" : "=v"(r) : "v"(lo), "v"(hi));
    return r;
}
DEV void gload_lds16(const void* g, void* l) {
    __builtin_amdgcn_global_load_lds((const __attribute__((address_space(1))) void*)g,
                                     (__attribute__((address_space(3))) void*)l, 16, 0, 0);
}

// ---------------- fused f32 -> bf16 convert for all 4 tensors (1 launch) ----------------
__global__ __launch_bounds__(256)
void cvt_all(const float* __restrict__ x, const float* __restrict__ qw,
             const float* __restrict__ kvw, const float* __restrict__ ow,
             u16* __restrict__ xo, u16* __restrict__ qo,
             u16* __restrict__ kvo, u16* __restrict__ oo) {
    const int i = blockIdx.x * 256 + threadIdx.x;   // 4,456,448 chunks exactly
    const float* src; u16* dst; int off;
    if (i < 2097152)      { src = x;   dst = xo;  off = i; }
    else if (i < 3145728) { src = qw;  dst = qo;  off = i - 2097152; }
    else if (i < 3407872) { src = kvw; dst = kvo; off = i - 3145728; }
    else                  { src = ow;  dst = oo;  off = i - 3407872; }
    f32x4 v = ((const f32x4*)src)[off];
    unsigned d0 = cvt_pk_bf16(v[0], v[1]);
    unsigned d1 = cvt_pk_bf16(v[2], v[3]);
    ((u64*)dst)[off] = (u64)d0 | ((u64)d1 << 32);
}

// ================= 256x128-tile 8-wave GEMM, counted vmcnt pipeline (R10 best) ======
template<int MODE>
__global__ __launch_bounds__(512, 1)
void gemm_bt2(const u16* __restrict__ A, const u16* __restrict__ B,
              const float* __restrict__ bias, void* __restrict__ Cout,
              const float* __restrict__ cosb, const float* __restrict__ sinb,
              float scale, int M, int N, int K) {
    __shared__ u16 Abuf[2][256 * 64];
    __shared__ u16 Bbuf[2][128 * 64];
    const int tid = threadIdx.x;
    const int w = tid >> 6, l = tid & 63;
    const int lr = l & 15, lg = l >> 4;
    const int wm = w >> 1, wn = w & 1;
    const int nbn = N >> 7;
    const int bm = blockIdx.x / nbn, bn = blockIdx.x % nbn;
    const int NT = K >> 6;
    const int rsel = l >> 3;
    const int csw = (l & 7) ^ rsel;   // inverse-swizzled source chunk (rule 21)
    const u16* Ag = A + ((size_t)(bm * 256) + rsel) * K + csw * 8;
    const u16* Bg = B + ((size_t)(bn * 128) + rsel) * K + csw * 8;

    f32x4 acc[4][4] = {};

#define STAGE(t, bufi) {                                                              \
        const int k0_ = (t) * 64;                                                     \
        _Pragma("unroll")                                                             \
        for (int j = 0; j < 4; ++j)                                                   \
            gload_lds16(Ag + (size_t)(w * 32 + j * 8) * K + k0_,                      \
                        &Abuf[bufi][(w * 32 + j * 8) * 64]);                          \
        _Pragma("unroll")                                                             \
        for (int j = 0; j < 2; ++j)                                                   \
            gload_lds16(Bg + (size_t)(w * 16 + j * 8) * K + k0_,                      \
                        &Bbuf[bufi][(w * 16 + j * 8) * 64]);                          \
    }

    STAGE(0, 0);
    STAGE(1, 1);

    #pragma unroll 2
    for (int t = 0; t < NT; ++t) {
        const int bufi = t & 1;
        if (t + 1 < NT) asm volatile("s_waitcnt vmcnt(6)" ::: "memory");
        else            asm volatile("s_waitcnt vmcnt(0)" ::: "memory");
        __builtin_amdgcn_s_barrier();

        s16x8 af[2][4], bf[2][4];
        #pragma unroll
        for (int ks = 0; ks < 2; ++ks) {
            #pragma unroll
            for (int mi = 0; mi < 4; ++mi) {
                const int row = wm * 64 + mi * 16 + lr;
                const int off = (row * 64 + ks * 32 + lg * 8) ^ ((row & 7) << 3);
                af[ks][mi] = *(const s16x8*)&Abuf[bufi][off];
            }
            #pragma unroll
            for (int ni = 0; ni < 4; ++ni) {
                const int row = wn * 32 + (ni & 1) * 16 + (ni >> 1) * 64 + lr;
                const int off = (row * 64 + ks * 32 + lg * 8) ^ ((row & 7) << 3);
                bf[ks][ni] = *(const s16x8*)&Bbuf[bufi][off];
            }
        }
        asm volatile("s_waitcnt lgkmcnt(0)" ::: "memory");
        __builtin_amdgcn_s_barrier();   // all waves done reading buf -> safe to restage

        if (t + 2 < NT) STAGE(t + 2, bufi);

        __builtin_amdgcn_s_setprio(1);
        #pragma unroll
        for (int ks = 0; ks < 2; ++ks)
            #pragma unroll
            for (int mi = 0; mi < 4; ++mi)
                #pragma unroll
                for (int ni = 0; ni < 4; ++ni)
                    acc[mi][ni] = __builtin_amdgcn_mfma_f32_16x16x32_bf16(af[ks][mi], bf[ks][ni], acc[mi][ni], 0, 0, 0);
        __builtin_amdgcn_s_setprio(0);
    }
#undef STAGE

    if (MODE == 0) {
        // fused bias + RoPE + scale, bf16 out
        #pragma unroll
        for (int ni = 0; ni < 2; ++ni) {
            const int d = wn * 32 + ni * 16 + lr;            // [0,64)
            const int col = bn * 128 + d;
            const float bv0 = bias[col];
            const float bv1 = bias[col + 64];
            #pragma unroll
            for (int mi = 0; mi < 4; ++mi) {
                #pragma unroll
                for (int r = 0; r < 4; ++r) {
                    const int row = bm * 256 + wm * 64 + mi * 16 + lg * 4 + r;
                    const int s = row & 2047;
                    const float c0 = cosb[s * 128 + d],      s0 = sinb[s * 128 + d];
                    const float c1 = cosb[s * 128 + d + 64], s1 = sinb[s * 128 + d + 64];
                    const float t0 = acc[mi][ni][r] + bv0;
                    const float t1 = acc[mi][ni + 2][r] + bv1;
                    ((u16*)Cout)[(size_t)row * N + col]      = bf16_rne((t0 * c0 - t1 * s0) * scale);
                    ((u16*)Cout)[(size_t)row * N + col + 64] = bf16_rne((t1 * c1 + t0 * s1) * scale);
                }
            }
        }
    } else {
        #pragma unroll
        for (int ni = 0; ni < 4; ++ni) {
            const int col = bn * 128 + wn * 32 + (ni & 1) * 16 + (ni >> 1) * 64 + lr;
            #pragma unroll
            for (int mi = 0; mi < 4; ++mi) {
                #pragma unroll
                for (int r = 0; r < 4; ++r) {
                    const int row = bm * 256 + wm * 64 + mi * 16 + lg * 4 + r;
                    ((float*)Cout)[(size_t)row * N + col] = acc[mi][ni][r];
                }
            }
        }
    }
}

// ---------------- KV-proj GEMM: 32x128 tile, 4-wave, grid 512 (R17) ----------------
// Tile 32 rows x 128 cols, per-wave 16x64 (acc[1][4]) -> grid 128x4 = 512 blocks
// = 2 blocks/CU (co-residency hides barrier stalls). Same rule-21 swizzle;
// K(rope)/V^T split epilogue.
__global__ __launch_bounds__(256)
void gemm_kv(const u16* __restrict__ A, const u16* __restrict__ B,
             const float* __restrict__ bias, void* __restrict__ Cout,
             void* __restrict__ Cout2, const float* __restrict__ cosb,
             const float* __restrict__ sinb, int M, int N, int K) {
    __shared__ u16 As[32 * 64];
    __shared__ u16 Bs[128 * 64];
    const int tid = threadIdx.x;
    const int w = tid >> 6, l = tid & 63;
    const int nbn = N >> 7;                // 4
    const int bm = blockIdx.x / nbn;       // [0,128)
    const int bn = blockIdx.x % nbn;
    const int wr = w >> 1, wc = w & 1;
    const int lr = l & 15, lg = l >> 4;
    const int rowsel = l >> 3;
    const int csw = (l & 7) ^ rowsel;   // inverse-swizzled source chunk (rule 21)
    const int rxor = (lr & 7) << 3;     // read-side XOR

    f32x4 acc[4] = {};

    const u16* Abase = A + (size_t)(bm * 32 + w * 8) * K;     // 8 rows per wave
    const u16* Bbase = B + (size_t)(bn * 128 + w * 32) * K;
    u16* AsW = As + (w * 8) * 64;
    u16* BsW = Bs + (w * 32) * 64;

    for (int k0 = 0; k0 < K; k0 += 64) {
        __syncthreads();
        gload_lds16(Abase + (size_t)rowsel * K + k0 + csw * 8, AsW);
        #pragma unroll
        for (int i = 0; i < 4; ++i)
            gload_lds16(Bbase + (size_t)(i * 8 + rowsel) * K + k0 + csw * 8, BsW + i * 8 * 64);
        __syncthreads();
        #pragma unroll
        for (int ks = 0; ks < 2; ++ks) {
            s16x8 af, bfr[4];
            af = *(const s16x8*)(As + (((wr * 16 + lr) * 64 + ks * 32 + lg * 8) ^ rxor));
            #pragma unroll
            for (int ni = 0; ni < 4; ++ni)
                bfr[ni] = *(const s16x8*)(Bs + (((wc * 32 + (ni & 1) * 16 + (ni >> 1) * 64 + lr) * 64 + ks * 32 + lg * 8) ^ rxor));
            #pragma unroll
            for (int ni = 0; ni < 4; ++ni)
                acc[ni] = __builtin_amdgcn_mfma_f32_16x16x32_bf16(af, bfr[ni], acc[ni], 0, 0, 0);
        }
    }

    const int row0 = bm * 32 + wr * 16;
    const int bb = row0 >> 11;
    if (bn < 2) {
        // K head kvh = bn, with fused RoPE (scale 1): pairs (ni, ni+2)
        #pragma unroll
        for (int ni = 0; ni < 2; ++ni) {
            const int d = wc * 32 + ni * 16 + lr;            // [0,64)
            const float bv0 = bias[bn * 128 + d];
            const float bv1 = bias[bn * 128 + d + 64];
            u16* kbase = (u16*)Cout + (size_t)(bb * 2 + bn) * 2048 * 128;
            #pragma unroll
            for (int r = 0; r < 4; ++r) {
                const int s = (row0 & 2047) + lg * 4 + r;
                const float c0 = cosb[s * 128 + d],      s0 = sinb[s * 128 + d];
                const float c1 = cosb[s * 128 + d + 64], s1 = sinb[s * 128 + d + 64];
                const float t0 = acc[ni][r] + bv0;
                const float t1 = acc[ni + 2][r] + bv1;
                kbase[(size_t)s * 128 + d]      = bf16_rne(t0 * c0 - t1 * s0);
                kbase[(size_t)s * 128 + d + 64] = bf16_rne(t1 * c1 + t0 * s1);
            }
        }
    } else {
        // V^T [b][kvh][d][s], packed 4-row bf16 writes
        #pragma unroll
        for (int ni = 0; ni < 4; ++ni) {
            const int d = wc * 32 + (ni & 1) * 16 + (ni >> 1) * 64 + lr;
            const int kvh = bn - 2;
            const float bv = bias[256 + kvh * 128 + d];
            const int s = (row0 & 2047) + lg * 4;
            unsigned d0 = cvt_pk_bf16(acc[ni][0] + bv, acc[ni][1] + bv);
            unsigned d1 = cvt_pk_bf16(acc[ni][2] + bv, acc[ni][3] + bv);
            *(u64*)((u16*)Cout2 + ((size_t)(bb * 2 + kvh) * 128 + d) * 2048 + s)
                = (u64)d0 | ((u64)d1 << 32);
        }
    }
}

// ---------------- causal GQA flash attention: 32x32 swapped-QK, in-register P (R15) ----
__global__ __launch_bounds__(256, 2)
void attn_fwd(const u16* __restrict__ Q, const u16* __restrict__ Kb,
              const u16* __restrict__ VTb, u16* __restrict__ O) {
    __shared__ u16 lds[2 * 64 * 128 + 2 * 128 * 64];   // K dbuf 32KB + V^T dbuf 32KB

    const int tid = threadIdx.x, w = tid >> 6, l = tid & 63;
    const int l31 = l & 31, hi = l >> 5;
    const int bi = blockIdx.x;
    const int half = bi >> 8, idx = bi & 255;
    const int bh = half * 16 + (idx >> 4);
    const int tq = idx & 15;
    const int tile = half ? (15 - tq) : tq;
    const int b = bh >> 4, h = bh & 15;
    const int kvh = h >> 3;
    const u16* Kg = Kb + (size_t)(b * 2 + kvh) * 2048 * 128;
    const u16* Vg = VTb + (size_t)(b * 2 + kvh) * 128 * 2048;

    // ---- Q fragments from global (L2-hot): lane q = l31, d = st*16 + hi*8 + j
    const int qrow = tile * 128 + w * 32 + l31;
    s16x8 qf[8];
    {
        const u16* Qrow = Q + ((size_t)(b * 2048 + qrow) * 2048 + h * 128);
        #pragma unroll
        for (int st = 0; st < 8; ++st)
            qf[st] = *(const s16x8*)(Qrow + st * 16 + hi * 8);
    }

    // stage K[64][128] + V^T[128][64] for k-tile kt into buffer (kt&1).
    auto stage = [&](int kt) {
        u16* Kd = lds + (kt & 1) * 8192;
        u16* Vd = lds + 16384 + (kt & 1) * 8192;
        #pragma unroll
        for (int j = 0; j < 4; ++j) {
            const int c = tid + j * 256;            // 1024 chunks: row = c>>4, col16 = c&15
            const int row = c >> 4;
            const int srcoff = ((c & 15) * 16) ^ ((row & 7) << 4);
            gload_lds16((const char*)Kg + (size_t)(kt * 64 + row) * 256 + srcoff,
                        (char*)Kd + c * 16);
        }
        #pragma unroll
        for (int j = 0; j < 4; ++j) {
            const int c = tid + j * 256;            // 1024 chunks: d = c>>3, k16 = c&7
            const int d = c >> 3;
            const int srcoff = ((c & 7) * 16) ^ ((d & 7) << 4);
            gload_lds16((const char*)Vg + (size_t)d * 4096 + (size_t)kt * 128 + srcoff,
                        (char*)Vd + c * 16);
        }
    };

    float m = -1e30f, lsum = 0.0f;
    f32x16 oacc[4] = {};

    const int ktend = 2 * tile + 2;
    stage(0);

    #pragma unroll 1
    for (int kt = 0; kt < ktend; ++kt) {
        const u16* Ks = lds + (kt & 1) * 8192;
        const u16* Vs = lds + 16384 + (kt & 1) * 8192;
        if (kt + 1 < ktend) {
            stage(kt + 1);                          // prefetch into other buffer
            asm volatile("s_waitcnt vmcnt(8)" ::: "memory");   // tile-kt landed
        } else {
            asm volatile("s_waitcnt vmcnt(0)" ::: "memory");
        }
        __builtin_amdgcn_s_barrier();               // raw: prefetch stays in flight

        // ---- swapped QK^T (32x32x16): S^T[k][q], A = K rows, B = Q cols
        f32x16 s0 = {}, s1 = {};
        #pragma unroll
        for (int st = 0; st < 8; ++st) {
            const int off0 = ((l31)*256 + st * 32 + hi * 16) ^ ((l31 & 7) << 4);
            const int off1 = ((l31 + 32) * 256 + st * 32 + hi * 16) ^ ((l31 & 7) << 4);
            s16x8 k0 = *(const s16x8*)((const char*)Ks + off0);
            s16x8 k1 = *(const s16x8*)((const char*)Ks + off1);
            s0 = __builtin_amdgcn_mfma_f32_32x32x16_bf16(k0, qf[st], s0, 0, 0, 0);
            s1 = __builtin_amdgcn_mfma_f32_32x32x16_bf16(k1, qf[st], s1, 0, 0, 0);
        }

        // ---- causal mask (only near diagonal) + online softmax, exp2 domain.
        if (kt >= 2 * tile) {
            #pragma unroll
            for (int r = 0; r < 16; ++r) {
                const int k0 = kt * 64 + (r & 3) + 8 * (r >> 2) + 4 * hi;
                if (k0 > qrow)      s0[r] = -1e30f;
                if (k0 + 32 > qrow) s1[r] = -1e30f;
            }
        }
        float mx = m;
        #pragma unroll
        for (int r = 0; r < 16; ++r) {
            mx = fmaxf(mx, s0[r]);
            mx = fmaxf(mx, s1[r]);
        }
        mx = fmaxf(mx, __shfl_xor(mx, 32, 64));     // combine lane halves (same q)
        const bool need = __any(mx > m + 11.5f);    // T13 defer-max (~8 nats)
        float corr = 1.0f;
        if (need) { corr = exp2f(m - mx); m = mx; }
        float rs = 0.0f;
        #pragma unroll
        for (int r = 0; r < 16; ++r) {
            const float p0 = exp2f(s0[r] - m);
            const float p1 = exp2f(s1[r] - m);
            s0[r] = p0; s1[r] = p1;
            rs += p0 + p1;
        }
        rs += __shfl_xor(rs, 32, 64);
        lsum = lsum * corr + rs;
        if (need) {                                 // rare: gather per-row corr
            #pragma unroll
            for (int r = 0; r < 16; ++r) {
                const int qr = (r & 3) + 8 * (r >> 2) + 4 * hi;
                const float cq = __shfl(corr, qr, 64);
                oacc[0][r] *= cq; oacc[1][r] *= cq;
                oacc[2][r] *= cq; oacc[3][r] *= cq;
            }
        }

        // ---- P -> PV A-frags in-register: 4 cvt_pk + 2 permlane32_swap per 16-k chunk
        s16x8 pa[4];
        #pragma unroll
        for (int c = 0; c < 4; ++c) {
            const int rb = (c & 1) * 8;
            float p0, p1, p2, p3, p4, p5, p6, p7;
            if (c < 2) {
                p0 = s0[rb+0]; p1 = s0[rb+1]; p2 = s0[rb+2]; p3 = s0[rb+3];
                p4 = s0[rb+4]; p5 = s0[rb+5]; p6 = s0[rb+6]; p7 = s0[rb+7];
            } else {
                p0 = s1[rb+0]; p1 = s1[rb+1]; p2 = s1[rb+2]; p3 = s1[rb+3];
                p4 = s1[rb+4]; p5 = s1[rb+5]; p6 = s1[rb+6]; p7 = s1[rb+7];
            }
            unsigned w01 = cvt_pk_bf16(p0, p1);     // lo: k(+0,+1) | hi: k(+4,+5)
            unsigned w23 = cvt_pk_bf16(p2, p3);
            unsigned w45 = cvt_pk_bf16(p4, p5);
            unsigned w67 = cvt_pk_bf16(p6, p7);
            asm volatile("v_permlane32_swap_b32 %0, %1" : "+v"(w01), "+v"(w45));
            asm volatile("v_permlane32_swap_b32 %0, %1" : "+v"(w23), "+v"(w67));
            u32x4 words = {w01, w23, w45, w67};     // k ascending: frag words 0..3
            pa[c] = __builtin_bit_cast(s16x8, words);
        }

        // ---- PV (32x32x16): O[q][d] += P[q][k] V[k][d]; B from swizzled V^T
        #pragma unroll
        for (int c = 0; c < 4; ++c) {
            #pragma unroll
            for (int nd = 0; nd < 4; ++nd) {
                const int row = nd * 32 + l31;
                const int boff = (row * 128 + c * 32 + hi * 16) ^ ((row & 7) << 4);
                s16x8 vf = *(const s16x8*)((const char*)Vs + boff);
                oacc[nd] = __builtin_amdgcn_mfma_f32_32x32x16_bf16(pa[c], vf, oacc[nd], 0, 0, 0);
            }
        }

        // reads of buf(kt&1) complete before next iter's stage lands there
        asm volatile("s_waitcnt lgkmcnt(0)" ::: "memory");
        __builtin_amdgcn_s_barrier();
    }

    // ---- epilogue: normalize (inv for row qr gathered from lane qr), write bf16
    const float inv = 1.0f / lsum;
    #pragma unroll
    for (int r = 0; r < 16; ++r) {
        const int qr = (r & 3) + 8 * (r >> 2) + 4 * hi;
        const float iq = __shfl(inv, qr, 64);
        const int q = tile * 128 + w * 32 + qr;
        u16* orow = O + ((size_t)(b * 2048 + q) * 2048 + h * 128 + l31);
        orow[0]  = bf16_rne(oacc[0][r] * iq);
        orow[32] = bf16_rne(oacc[1][r] * iq);
        orow[64] = bf16_rne(oacc[2][r] * iq);
        orow[96] = bf16_rne(oacc[3][r] * iq);
    }
}

// ---------------- launch ----------------
extern "C" void kernel_launch(void* const* d_in, const int* in_sizes, int n_in,
                              void* d_out, int out_size, void* d_ws, size_t ws_size,
                              hipStream_t stream) {
    const float* x    = (const float*)d_in[0];
    const float* cosb = (const float*)d_in[1];
    const float* sinb = (const float*)d_in[2];
    const float* q_w  = (const float*)d_in[3];
    const float* q_b  = (const float*)d_in[4];
    const float* kv_w = (const float*)d_in[5];
    const float* kv_b = (const float*)d_in[6];
    const float* o_w  = (const float*)d_in[7];
    float* out = (float*)d_out;

    char* p = (char*)d_ws;
    u16* x_bf   = (u16*)p; p += (size_t)4096 * 2048 * 2;
    u16* qw_bf  = (u16*)p; p += (size_t)2048 * 2048 * 2;
    u16* kvw_bf = (u16*)p; p += (size_t)512 * 2048 * 2;
    u16* ow_bf  = (u16*)p; p += (size_t)2048 * 2048 * 2;
    u16* q_bf   = (u16*)p; p += (size_t)4096 * 2048 * 2;
    u16* k_bf   = (u16*)p; p += (size_t)4 * 2048 * 128 * 2;   // [b][kvh][s][d]
    u16* vt_bf  = (u16*)p; p += (size_t)4 * 128 * 2048 * 2;   // [b][kvh][d][s]
    u16* at_bf  = (u16*)p; p += (size_t)4096 * 2048 * 2;

    cvt_all<<<17408, 256, 0, stream>>>(x, q_w, kv_w, o_w, x_bf, qw_bf, kvw_bf, ow_bf);

    // Q-proj with fused RoPE + score scaling (1/sqrt(128) * log2(e): exp2 domain)
    const float qk_scale2 = 0.12751744517764862f;
    gemm_bt2<0><<<dim3(16 * 16), 512, 0, stream>>>(x_bf, qw_bf, q_b, q_bf,
                                                   cosb, sinb, qk_scale2, 4096, 2048, 2048);
    gemm_kv<<<dim3(128 * 4), 256, 0, stream>>>(x_bf, kvw_bf, kv_b, k_bf, vt_bf,
                                               cosb, sinb, 4096, 512, 2048);

    attn_fwd<<<dim3(512), 256, 0, stream>>>(q_bf, k_bf, vt_bf, at_bf);

    gemm_bt2<1><<<dim3(16 * 16), 512, 0, stream>>>(at_bf, ow_bf, nullptr, out,
                                                   nullptr, nullptr, 0.0f, 4096, 2048, 2048);
}

// Round 18
// 186.141 us; speedup vs baseline: 1.1053x; 1.0483x over previous
//
#include <hip/hip_runtime.h>

typedef unsigned short u16;
typedef unsigned long long u64;
typedef __attribute__((ext_vector_type(4))) unsigned u32x4;
typedef __attribute__((ext_vector_type(4))) float f32x4;
typedef __attribute__((ext_vector_type(16))) float f32x16;
typedef __attribute__((ext_vector_type(8))) short s16x8;

#define DEV __device__ __forceinline__

DEV u16 bf16_rne(float f) {
    unsigned u = __builtin_bit_cast(unsigned, f);
    u += 0x7fffu + ((u >> 16) & 1u);
    return (u16)(u >> 16);
}
DEV unsigned cvt_pk_bf16(float lo, float hi) {   // packed f32x2 -> bf16x2 (1 instr)
    unsigned r;
    asm("v_cvt_pk_bf16_f32 %0, %1, %2" : "=v"(r) : "v"(lo), "v"(hi));
    return r;
}
DEV void gload_lds16(const void* g, void* l) {
    __builtin_amdgcn_global_load_lds((const __attribute__((address_space(1))) void*)g,
                                     (__attribute__((address_space(3))) void*)l, 16, 0, 0);
}

// ---------------- fused f32 -> bf16 convert for all 4 tensors (1 launch) ----------------
__global__ __launch_bounds__(256)
void cvt_all(const float* __restrict__ x, const float* __restrict__ qw,
             const float* __restrict__ kvw, const float* __restrict__ ow,
             u16* __restrict__ xo, u16* __restrict__ qo,
             u16* __restrict__ kvo, u16* __restrict__ oo) {
    const int i = blockIdx.x * 256 + threadIdx.x;   // 4,456,448 chunks exactly
    const float* src; u16* dst; int off;
    if (i < 2097152)      { src = x;   dst = xo;  off = i; }
    else if (i < 3145728) { src = qw;  dst = qo;  off = i - 2097152; }
    else if (i < 3407872) { src = kvw; dst = kvo; off = i - 3145728; }
    else                  { src = ow;  dst = oo;  off = i - 3407872; }
    f32x4 v = ((const f32x4*)src)[off];
    unsigned d0 = cvt_pk_bf16(v[0], v[1]);
    unsigned d1 = cvt_pk_bf16(v[2], v[3]);
    ((u64*)dst)[off] = (u64)d0 | ((u64)d1 << 32);
}

// ====== 128x128-tile 4-wave GEMM, counted vmcnt pipeline (R18: m103-verified config) ===
// Tile 128x128, BK=64, 256 threads (2x2 waves, per-wave 64x64). LDS dbuf 64KB ->
// 2 blocks/CU (co-resident block hides barrier/vmcnt stalls — same mechanism as R17's
// gemm_kv win; m103 measured 912 TF at this structure). Counted vmcnt(8): 8 loads/
// thread/tile, stage(t+2) issued after the read-seal barrier -> one full iteration of
// flight. Rule-21 XOR swizzle both sides. MODE 0: bf16 + bias + fused RoPE (col map
// pairs (d,d+64) in-wave). MODE 1: f32 out.
template<int MODE>
__global__ __launch_bounds__(256, 2)
void gemm_bt2(const u16* __restrict__ A, const u16* __restrict__ B,
              const float* __restrict__ bias, void* __restrict__ Cout,
              const float* __restrict__ cosb, const float* __restrict__ sinb,
              float scale, int M, int N, int K) {
    __shared__ u16 Abuf[2][128 * 64];
    __shared__ u16 Bbuf[2][128 * 64];
    const int tid = threadIdx.x;
    const int w = tid >> 6, l = tid & 63;
    const int lr = l & 15, lg = l >> 4;
    const int wm = w >> 1, wn = w & 1;
    const int nbn = N >> 7;
    const int bm = blockIdx.x / nbn, bn = blockIdx.x % nbn;
    const int NT = K >> 6;
    const int rsel = l >> 3;
    const int csw = (l & 7) ^ rsel;   // inverse-swizzled source chunk (rule 21)
    const int rxor = (lr & 7) << 3;   // read-side XOR (row&7 == lr&7 for all frags)
    const u16* Ag = A + ((size_t)(bm * 128) + rsel) * K + csw * 8;
    const u16* Bg = B + ((size_t)(bn * 128) + rsel) * K + csw * 8;

    f32x4 acc[4][4] = {};

#define STAGE(t, bufi) {                                                              \
        const int k0_ = (t) * 64;                                                     \
        _Pragma("unroll")                                                             \
        for (int j = 0; j < 4; ++j)                                                   \
            gload_lds16(Ag + (size_t)(w * 32 + j * 8) * K + k0_,                      \
                        &Abuf[bufi][(w * 32 + j * 8) * 64]);                          \
        _Pragma("unroll")                                                             \
        for (int j = 0; j < 4; ++j)                                                   \
            gload_lds16(Bg + (size_t)(w * 32 + j * 8) * K + k0_,                      \
                        &Bbuf[bufi][(w * 32 + j * 8) * 64]);                          \
    }

    STAGE(0, 0);
    STAGE(1, 1);

    #pragma unroll 2
    for (int t = 0; t < NT; ++t) {
        const int bufi = t & 1;
        if (t + 1 < NT) asm volatile("s_waitcnt vmcnt(8)" ::: "memory");  // tile-t landed
        else            asm volatile("s_waitcnt vmcnt(0)" ::: "memory");
        __builtin_amdgcn_s_barrier();

        s16x8 af[2][4], bf[2][4];
        #pragma unroll
        for (int ks = 0; ks < 2; ++ks) {
            #pragma unroll
            for (int mi = 0; mi < 4; ++mi) {
                const int row = wm * 64 + mi * 16 + lr;
                const int off = (row * 64 + ks * 32 + lg * 8) ^ rxor;
                af[ks][mi] = *(const s16x8*)&Abuf[bufi][off];
            }
            #pragma unroll
            for (int ni = 0; ni < 4; ++ni) {
                const int row = wn * 32 + (ni & 1) * 16 + (ni >> 1) * 64 + lr;
                const int off = (row * 64 + ks * 32 + lg * 8) ^ rxor;
                bf[ks][ni] = *(const s16x8*)&Bbuf[bufi][off];
            }
        }
        asm volatile("s_waitcnt lgkmcnt(0)" ::: "memory");
        __builtin_amdgcn_s_barrier();   // all waves done reading buf -> safe to restage

        if (t + 2 < NT) STAGE(t + 2, bufi);

        __builtin_amdgcn_s_setprio(1);
        #pragma unroll
        for (int ks = 0; ks < 2; ++ks)
            #pragma unroll
            for (int mi = 0; mi < 4; ++mi)
                #pragma unroll
                for (int ni = 0; ni < 4; ++ni)
                    acc[mi][ni] = __builtin_amdgcn_mfma_f32_16x16x32_bf16(af[ks][mi], bf[ks][ni], acc[mi][ni], 0, 0, 0);
        __builtin_amdgcn_s_setprio(0);
    }
#undef STAGE

    if (MODE == 0) {
        // fused bias + RoPE + scale, bf16 out
        #pragma unroll
        for (int ni = 0; ni < 2; ++ni) {
            const int d = wn * 32 + ni * 16 + lr;            // [0,64)
            const int col = bn * 128 + d;
            const float bv0 = bias[col];
            const float bv1 = bias[col + 64];
            #pragma unroll
            for (int mi = 0; mi < 4; ++mi) {
                #pragma unroll
                for (int r = 0; r < 4; ++r) {
                    const int row = bm * 128 + wm * 64 + mi * 16 + lg * 4 + r;
                    const int s = row & 2047;
                    const float c0 = cosb[s * 128 + d],      s0 = sinb[s * 128 + d];
                    const float c1 = cosb[s * 128 + d + 64], s1 = sinb[s * 128 + d + 64];
                    const float t0 = acc[mi][ni][r] + bv0;
                    const float t1 = acc[mi][ni + 2][r] + bv1;
                    ((u16*)Cout)[(size_t)row * N + col]      = bf16_rne((t0 * c0 - t1 * s0) * scale);
                    ((u16*)Cout)[(size_t)row * N + col + 64] = bf16_rne((t1 * c1 + t0 * s1) * scale);
                }
            }
        }
    } else {
        #pragma unroll
        for (int ni = 0; ni < 4; ++ni) {
            const int col = bn * 128 + wn * 32 + (ni & 1) * 16 + (ni >> 1) * 64 + lr;
            #pragma unroll
            for (int mi = 0; mi < 4; ++mi) {
                #pragma unroll
                for (int r = 0; r < 4; ++r) {
                    const int row = bm * 128 + wm * 64 + mi * 16 + lg * 4 + r;
                    ((float*)Cout)[(size_t)row * N + col] = acc[mi][ni][r];
                }
            }
        }
    }
}

// ---------------- KV-proj GEMM: 32x128 tile, 4-wave, grid 512 (R17 best) ----------------
__global__ __launch_bounds__(256)
void gemm_kv(const u16* __restrict__ A, const u16* __restrict__ B,
             const float* __restrict__ bias, void* __restrict__ Cout,
             void* __restrict__ Cout2, const float* __restrict__ cosb,
             const float* __restrict__ sinb, int M, int N, int K) {
    __shared__ u16 As[32 * 64];
    __shared__ u16 Bs[128 * 64];
    const int tid = threadIdx.x;
    const int w = tid >> 6, l = tid & 63;
    const int nbn = N >> 7;                // 4
    const int bm = blockIdx.x / nbn;       // [0,128)
    const int bn = blockIdx.x % nbn;
    const int wr = w >> 1, wc = w & 1;
    const int lr = l & 15, lg = l >> 4;
    const int rowsel = l >> 3;
    const int csw = (l & 7) ^ rowsel;   // inverse-swizzled source chunk (rule 21)
    const int rxor = (lr & 7) << 3;     // read-side XOR

    f32x4 acc[4] = {};

    const u16* Abase = A + (size_t)(bm * 32 + w * 8) * K;     // 8 rows per wave
    const u16* Bbase = B + (size_t)(bn * 128 + w * 32) * K;
    u16* AsW = As + (w * 8) * 64;
    u16* BsW = Bs + (w * 32) * 64;

    for (int k0 = 0; k0 < K; k0 += 64) {
        __syncthreads();
        gload_lds16(Abase + (size_t)rowsel * K + k0 + csw * 8, AsW);
        #pragma unroll
        for (int i = 0; i < 4; ++i)
            gload_lds16(Bbase + (size_t)(i * 8 + rowsel) * K + k0 + csw * 8, BsW + i * 8 * 64);
        __syncthreads();
        #pragma unroll
        for (int ks = 0; ks < 2; ++ks) {
            s16x8 af, bfr[4];
            af = *(const s16x8*)(As + (((wr * 16 + lr) * 64 + ks * 32 + lg * 8) ^ rxor));
            #pragma unroll
            for (int ni = 0; ni < 4; ++ni)
                bfr[ni] = *(const s16x8*)(Bs + (((wc * 32 + (ni & 1) * 16 + (ni >> 1) * 64 + lr) * 64 + ks * 32 + lg * 8) ^ rxor));
            #pragma unroll
            for (int ni = 0; ni < 4; ++ni)
                acc[ni] = __builtin_amdgcn_mfma_f32_16x16x32_bf16(af, bfr[ni], acc[ni], 0, 0, 0);
        }
    }

    const int row0 = bm * 32 + wr * 16;
    const int bb = row0 >> 11;
    if (bn < 2) {
        // K head kvh = bn, with fused RoPE (scale 1): pairs (ni, ni+2)
        #pragma unroll
        for (int ni = 0; ni < 2; ++ni) {
            const int d = wc * 32 + ni * 16 + lr;            // [0,64)
            const float bv0 = bias[bn * 128 + d];
            const float bv1 = bias[bn * 128 + d + 64];
            u16* kbase = (u16*)Cout + (size_t)(bb * 2 + bn) * 2048 * 128;
            #pragma unroll
            for (int r = 0; r < 4; ++r) {
                const int s = (row0 & 2047) + lg * 4 + r;
                const float c0 = cosb[s * 128 + d],      s0 = sinb[s * 128 + d];
                const float c1 = cosb[s * 128 + d + 64], s1 = sinb[s * 128 + d + 64];
                const float t0 = acc[ni][r] + bv0;
                const float t1 = acc[ni + 2][r] + bv1;
                kbase[(size_t)s * 128 + d]      = bf16_rne(t0 * c0 - t1 * s0);
                kbase[(size_t)s * 128 + d + 64] = bf16_rne(t1 * c1 + t0 * s1);
            }
        }
    } else {
        // V^T [b][kvh][d][s], packed 4-row bf16 writes
        #pragma unroll
        for (int ni = 0; ni < 4; ++ni) {
            const int d = wc * 32 + (ni & 1) * 16 + (ni >> 1) * 64 + lr;
            const int kvh = bn - 2;
            const float bv = bias[256 + kvh * 128 + d];
            const int s = (row0 & 2047) + lg * 4;
            unsigned d0 = cvt_pk_bf16(acc[ni][0] + bv, acc[ni][1] + bv);
            unsigned d1 = cvt_pk_bf16(acc[ni][2] + bv, acc[ni][3] + bv);
            *(u64*)((u16*)Cout2 + ((size_t)(bb * 2 + kvh) * 128 + d) * 2048 + s)
                = (u64)d0 | ((u64)d1 << 32);
        }
    }
}

// ---------------- causal GQA flash attention: 32x32 swapped-QK, in-register P (R15) ----
__global__ __launch_bounds__(256, 2)
void attn_fwd(const u16* __restrict__ Q, const u16* __restrict__ Kb,
              const u16* __restrict__ VTb, u16* __restrict__ O) {
    __shared__ u16 lds[2 * 64 * 128 + 2 * 128 * 64];   // K dbuf 32KB + V^T dbuf 32KB

    const int tid = threadIdx.x, w = tid >> 6, l = tid & 63;
    const int l31 = l & 31, hi = l >> 5;
    const int bi = blockIdx.x;
    const int half = bi >> 8, idx = bi & 255;
    const int bh = half * 16 + (idx >> 4);
    const int tq = idx & 15;
    const int tile = half ? (15 - tq) : tq;
    const int b = bh >> 4, h = bh & 15;
    const int kvh = h >> 3;
    const u16* Kg = Kb + (size_t)(b * 2 + kvh) * 2048 * 128;
    const u16* Vg = VTb + (size_t)(b * 2 + kvh) * 128 * 2048;

    // ---- Q fragments from global (L2-hot): lane q = l31, d = st*16 + hi*8 + j
    const int qrow = tile * 128 + w * 32 + l31;
    s16x8 qf[8];
    {
        const u16* Qrow = Q + ((size_t)(b * 2048 + qrow) * 2048 + h * 128);
        #pragma unroll
        for (int st = 0; st < 8; ++st)
            qf[st] = *(const s16x8*)(Qrow + st * 16 + hi * 8);
    }

    // stage K[64][128] + V^T[128][64] for k-tile kt into buffer (kt&1).
    auto stage = [&](int kt) {
        u16* Kd = lds + (kt & 1) * 8192;
        u16* Vd = lds + 16384 + (kt & 1) * 8192;
        #pragma unroll
        for (int j = 0; j < 4; ++j) {
            const int c = tid + j * 256;            // 1024 chunks: row = c>>4, col16 = c&15
            const int row = c >> 4;
            const int srcoff = ((c & 15) * 16) ^ ((row & 7) << 4);
            gload_lds16((const char*)Kg + (size_t)(kt * 64 + row) * 256 + srcoff,
                        (char*)Kd + c * 16);
        }
        #pragma unroll
        for (int j = 0; j < 4; ++j) {
            const int c = tid + j * 256;            // 1024 chunks: d = c>>3, k16 = c&7
            const int d = c >> 3;
            const int srcoff = ((c & 7) * 16) ^ ((d & 7) << 4);
            gload_lds16((const char*)Vg + (size_t)d * 4096 + (size_t)kt * 128 + srcoff,
                        (char*)Vd + c * 16);
        }
    };

    float m = -1e30f, lsum = 0.0f;
    f32x16 oacc[4] = {};

    const int ktend = 2 * tile + 2;
    stage(0);

    #pragma unroll 1
    for (int kt = 0; kt < ktend; ++kt) {
        const u16* Ks = lds + (kt & 1) * 8192;
        const u16* Vs = lds + 16384 + (kt & 1) * 8192;
        if (kt + 1 < ktend) {
            stage(kt + 1);                          // prefetch into other buffer
            asm volatile("s_waitcnt vmcnt(8)" ::: "memory");   // tile-kt landed
        } else {
            asm volatile("s_waitcnt vmcnt(0)" ::: "memory");
        }
        __builtin_amdgcn_s_barrier();               // raw: prefetch stays in flight

        // ---- swapped QK^T (32x32x16): S^T[k][q], A = K rows, B = Q cols
        f32x16 s0 = {}, s1 = {};
        #pragma unroll
        for (int st = 0; st < 8; ++st) {
            const int off0 = ((l31)*256 + st * 32 + hi * 16) ^ ((l31 & 7) << 4);
            const int off1 = ((l31 + 32) * 256 + st * 32 + hi * 16) ^ ((l31 & 7) << 4);
            s16x8 k0 = *(const s16x8*)((const char*)Ks + off0);
            s16x8 k1 = *(const s16x8*)((const char*)Ks + off1);
            s0 = __builtin_amdgcn_mfma_f32_32x32x16_bf16(k0, qf[st], s0, 0, 0, 0);
            s1 = __builtin_amdgcn_mfma_f32_32x32x16_bf16(k1, qf[st], s1, 0, 0, 0);
        }

        // ---- causal mask (only near diagonal) + online softmax, exp2 domain.
        if (kt >= 2 * tile) {
            #pragma unroll
            for (int r = 0; r < 16; ++r) {
                const int k0 = kt * 64 + (r & 3) + 8 * (r >> 2) + 4 * hi;
                if (k0 > qrow)      s0[r] = -1e30f;
                if (k0 + 32 > qrow) s1[r] = -1e30f;
            }
        }
        float mx = m;
        #pragma unroll
        for (int r = 0; r < 16; ++r) {
            mx = fmaxf(mx, s0[r]);
            mx = fmaxf(mx, s1[r]);
        }
        mx = fmaxf(mx, __shfl_xor(mx, 32, 64));     // combine lane halves (same q)
        const bool need = __any(mx > m + 11.5f);    // T13 defer-max (~8 nats)
        float corr = 1.0f;
        if (need) { corr = exp2f(m - mx); m = mx; }
        float rs = 0.0f;
        #pragma unroll
        for (int r = 0; r < 16; ++r) {
            const float p0 = exp2f(s0[r] - m);
            const float p1 = exp2f(s1[r] - m);
            s0[r] = p0; s1[r] = p1;
            rs += p0 + p1;
        }
        rs += __shfl_xor(rs, 32, 64);
        lsum = lsum * corr + rs;
        if (need) {                                 // rare: gather per-row corr
            #pragma unroll
            for (int r = 0; r < 16; ++r) {
                const int qr = (r & 3) + 8 * (r >> 2) + 4 * hi;
                const float cq = __shfl(corr, qr, 64);
                oacc[0][r] *= cq; oacc[1][r] *= cq;
                oacc[2][r] *= cq; oacc[3][r] *= cq;
            }
        }

        // ---- P -> PV A-frags in-register: 4 cvt_pk + 2 permlane32_swap per 16-k chunk
        s16x8 pa[4];
        #pragma unroll
        for (int c = 0; c < 4; ++c) {
            const int rb = (c & 1) * 8;
            float p0, p1, p2, p3, p4, p5, p6, p7;
            if (c < 2) {
                p0 = s0[rb+0]; p1 = s0[rb+1]; p2 = s0[rb+2]; p3 = s0[rb+3];
                p4 = s0[rb+4]; p5 = s0[rb+5]; p6 = s0[rb+6]; p7 = s0[rb+7];
            } else {
                p0 = s1[rb+0]; p1 = s1[rb+1]; p2 = s1[rb+2]; p3 = s1[rb+3];
                p4 = s1[rb+4]; p5 = s1[rb+5]; p6 = s1[rb+6]; p7 = s1[rb+7];
            }
            unsigned w01 = cvt_pk_bf16(p0, p1);     // lo: k(+0,+1) | hi: k(+4,+5)
            unsigned w23 = cvt_pk_bf16(p2, p3);
            unsigned w45 = cvt_pk_bf16(p4, p5);
            unsigned w67 = cvt_pk_bf16(p6, p7);
            asm volatile("v_permlane32_swap_b32 %0, %1" : "+v"(w01), "+v"(w45));
            asm volatile("v_permlane32_swap_b32 %0, %1" : "+v"(w23), "+v"(w67));
            u32x4 words = {w01, w23, w45, w67};     // k ascending: frag words 0..3
            pa[c] = __builtin_bit_cast(s16x8, words);
        }

        // ---- PV (32x32x16): O[q][d] += P[q][k] V[k][d]; B from swizzled V^T
        #pragma unroll
        for (int c = 0; c < 4; ++c) {
            #pragma unroll
            for (int nd = 0; nd < 4; ++nd) {
                const int row = nd * 32 + l31;
                const int boff = (row * 128 + c * 32 + hi * 16) ^ ((row & 7) << 4);
                s16x8 vf = *(const s16x8*)((const char*)Vs + boff);
                oacc[nd] = __builtin_amdgcn_mfma_f32_32x32x16_bf16(pa[c], vf, oacc[nd], 0, 0, 0);
            }
        }

        // reads of buf(kt&1) complete before next iter's stage lands there
        asm volatile("s_waitcnt lgkmcnt(0)" ::: "memory");
        __builtin_amdgcn_s_barrier();
    }

    // ---- epilogue: normalize (inv for row qr gathered from lane qr), write bf16
    const float inv = 1.0f / lsum;
    #pragma unroll
    for (int r = 0; r < 16; ++r) {
        const int qr = (r & 3) + 8 * (r >> 2) + 4 * hi;
        const float iq = __shfl(inv, qr, 64);
        const int q = tile * 128 + w * 32 + qr;
        u16* orow = O + ((size_t)(b * 2048 + q) * 2048 + h * 128 + l31);
        orow[0]  = bf16_rne(oacc[0][r] * iq);
        orow[32] = bf16_rne(oacc[1][r] * iq);
        orow[64] = bf16_rne(oacc[2][r] * iq);
        orow[96] = bf16_rne(oacc[3][r] * iq);
    }
}

// ---------------- launch ----------------
extern "C" void kernel_launch(void* const* d_in, const int* in_sizes, int n_in,
                              void* d_out, int out_size, void* d_ws, size_t ws_size,
                              hipStream_t stream) {
    const float* x    = (const float*)d_in[0];
    const float* cosb = (const float*)d_in[1];
    const float* sinb = (const float*)d_in[2];
    const float* q_w  = (const float*)d_in[3];
    const float* q_b  = (const float*)d_in[4];
    const float* kv_w = (const float*)d_in[5];
    const float* kv_b = (const float*)d_in[6];
    const float* o_w  = (const float*)d_in[7];
    float* out = (float*)d_out;

    char* p = (char*)d_ws;
    u16* x_bf   = (u16*)p; p += (size_t)4096 * 2048 * 2;
    u16* qw_bf  = (u16*)p; p += (size_t)2048 * 2048 * 2;
    u16* kvw_bf = (u16*)p; p += (size_t)512 * 2048 * 2;
    u16* ow_bf  = (u16*)p; p += (size_t)2048 * 2048 * 2;
    u16* q_bf   = (u16*)p; p += (size_t)4096 * 2048 * 2;
    u16* k_bf   = (u16*)p; p += (size_t)4 * 2048 * 128 * 2;   // [b][kvh][s][d]
    u16* vt_bf  = (u16*)p; p += (size_t)4 * 128 * 2048 * 2;   // [b][kvh][d][s]
    u16* at_bf  = (u16*)p; p += (size_t)4096 * 2048 * 2;

    cvt_all<<<17408, 256, 0, stream>>>(x, q_w, kv_w, o_w, x_bf, qw_bf, kvw_bf, ow_bf);

    // Q-proj with fused RoPE + score scaling (1/sqrt(128) * log2(e): exp2 domain)
    const float qk_scale2 = 0.12751744517764862f;
    gemm_bt2<0><<<dim3(32 * 16), 256, 0, stream>>>(x_bf, qw_bf, q_b, q_bf,
                                                   cosb, sinb, qk_scale2, 4096, 2048, 2048);
    gemm_kv<<<dim3(128 * 4), 256, 0, stream>>>(x_bf, kvw_bf, kv_b, k_bf, vt_bf,
                                               cosb, sinb, 4096, 512, 2048);

    attn_fwd<<<dim3(512), 256, 0, stream>>>(q_bf, k_bf, vt_bf, at_bf);

    gemm_bt2<1><<<dim3(32 * 16), 256, 0, stream>>>(at_bf, ow_bf, nullptr, out,
                                                   nullptr, nullptr, 0.0f, 4096, 2048, 2048);
}